// Round 10
// baseline (127.377 us; speedup 1.0000x reference)
//
#include <hip/hip_runtime.h>

#define NV    6890
#define NCOL  192            // 64*3 output columns per row
#define CAP_W 512            // per-wave LDS nonzero capacity (saturating)
#define MAIN4 1722           // aligned float4 count per row ( (NV-2)/4 )
#define SCALE (1.0f / (64.0f * 6890.0f))

// ---------------------------------------------------------------------------
// Kernel 1: transpose x[b][w][d] -> Xt[w][b*3+d] (writes coalesced, reads
// L2-absorbed) + zero the scalar output (kernel boundary orders it before
// the lap kernel's atomics).
// ---------------------------------------------------------------------------
__global__ __launch_bounds__(256) void transpose_x_kernel(
    const float* __restrict__ x, float* __restrict__ Xt,
    float* __restrict__ out) {
  if (blockIdx.x == 0 && threadIdx.x == 0) out[0] = 0.0f;
  int i = blockIdx.x * blockDim.x + threadIdx.x;
  const int total = NV * NCOL;
  if (i >= total) return;
  int n = i % NCOL;
  int w = i / NCOL;
  Xt[i] = x[(size_t)(n / 3) * (NV * 3) + (size_t)w * 3 + (n % 3)];
}

// ---------------------------------------------------------------------------
// Kernel 2: ONE WAVE per row (R1 structure, best measured). Zero barriers.
//  Scan: float4 loads, value-granular ballot+popc prefix compaction into a
//        per-wave LDS list; SATURATING (no in-loop flush -> nothing blocks
//        the compiler from pipelining the row loads).
//  Apply: uniform-count loop, LDS broadcast, 3 coalesced 256B gathers from
//        Xt per entry. Row result atomicAdd'd to out (order-jitter ~1e-4,
//        far under threshold).
// ---------------------------------------------------------------------------
__global__ __launch_bounds__(256) void lap_rows_wave_kernel(
    const float* __restrict__ L, const float* __restrict__ Xt,
    float* __restrict__ out) {
  const int lane = threadIdx.x & 63;
  const int wv   = threadIdx.x >> 6;
  const int v    = blockIdx.x * 4 + wv;
  if (v >= NV) return;                    // whole-wave exit; no barriers used

  __shared__ float s_val[4][CAP_W];
  __shared__ int   s_idx[4][CAP_W];
  float* __restrict__ sval = s_val[wv];
  int*   __restrict__ sidx = s_idx[wv];

  const float* __restrict__ row = L + (size_t)v * NV;
  const int head     = (v & 1) ? 2 : 0;            // odd rows: 8B-misaligned start
  const int extraPos = head ? 0 : (NV - 2);        // the 2 floats outside f4 body
  const float4* __restrict__ m4 = (const float4*)(row + head);
  const unsigned long long lmask = (1ull << lane) - 1ull;

  // Column ownership: lane handles columns {lane, lane+64, lane+128} of Xt.
  const int n0 = lane, n1 = lane + 64, n2 = lane + 128;

  float a0 = 0.f, a1 = 0.f, a2 = 0.f;
  int nnz = 0;                                     // wave-uniform

  auto push = [&](bool nz, float val, int col) {   // saturating list append
    unsigned long long m = __ballot(nz);
    int pos = nnz + __popcll(m & lmask);
    if (nz && pos < CAP_W) { sval[pos] = val; sidx[pos] = col; }
    nnz += __popcll(m);                            // keeps counting past CAP_W
  };

  // ---- Phase 1: scan (loads + ballots + LDS stores only) -------------------
  {  // 2-float head (odd rows) / tail (even rows)
    const bool act = lane < 2;
    const float val = act ? row[extraPos + lane] : 0.f;
    push(act && val != 0.f, val, extraPos + lane);
  }

  for (int it = 0; it < 27; ++it) {
    const int i = it * 64 + lane;
    const bool act = i < MAIN4;
    float4 f = make_float4(0.f, 0.f, 0.f, 0.f);
    if (act) f = m4[i];
    const int cb = head + i * 4;
    push(act && f.x != 0.f, f.x, cb);
    push(act && f.y != 0.f, f.y, cb + 1);
    push(act && f.z != 0.f, f.z, cb + 2);
    push(act && f.w != 0.f, f.w, cb + 3);
  }

  // ---- Phase 2: apply ------------------------------------------------------
  if (nnz <= CAP_W) {
    const int cnt = nnz;
    #pragma unroll 4
    for (int j = 0; j < cnt; ++j) {                // uniform j: LDS broadcast
      const float val = sval[j];
      const float* __restrict__ xr = Xt + (size_t)sidx[j] * NCOL;
      a0 = fmaf(val, xr[n0], a0);
      a1 = fmaf(val, xr[n1], a1);
      a2 = fmaf(val, xr[n2], a2);
    }
  } else {
    // Pathological row (>CAP_W nonzeros; never for this input): dense re-walk.
    a0 = a1 = a2 = 0.f;
    auto walk = [&](unsigned long long m, float src, int col0, int stride) {
      while (m) {
        const int s = (int)__builtin_ctzll(m);
        m &= m - 1;
        const float val =
            __int_as_float(__builtin_amdgcn_readlane(__float_as_int(src), s));
        const float* __restrict__ xr = Xt + (size_t)(col0 + s * stride) * NCOL;
        a0 = fmaf(val, xr[n0], a0);
        a1 = fmaf(val, xr[n1], a1);
        a2 = fmaf(val, xr[n2], a2);
      }
    };
    {
      const bool act = lane < 2;
      const float val = act ? row[extraPos + lane] : 0.f;
      walk(__ballot(act && val != 0.f), val, extraPos, 1);
    }
    for (int it = 0; it < 27; ++it) {
      const int i = it * 64 + lane;
      const bool act = i < MAIN4;
      float4 f = make_float4(0.f, 0.f, 0.f, 0.f);
      if (act) f = m4[i];
      const int cb = head + it * 256;
      walk(__ballot(act && f.x != 0.f), f.x, cb + 0, 4);
      walk(__ballot(act && f.y != 0.f), f.y, cb + 1, 4);
      walk(__ballot(act && f.z != 0.f), f.z, cb + 2, 4);
      walk(__ballot(act && f.w != 0.f), f.w, cb + 3, 4);
    }
  }

  // ---- Row contribution: wave-reduce sum of squares, one atomic per row ----
  float sq = fmaf(a0, a0, fmaf(a1, a1, a2 * a2));
  #pragma unroll
  for (int o = 32; o > 0; o >>= 1) sq += __shfl_down(sq, o);
  if (lane == 0) atomicAdd(out, sq * SCALE);
}

// ---------------------------------------------------------------------------
// Fallback (tiny ws): fused bit-walk gathering from x directly + atomic out.
// ---------------------------------------------------------------------------
__global__ __launch_bounds__(256) void lap_fused_kernel(
    const float* __restrict__ L, const float* __restrict__ x,
    float* __restrict__ out) {
  const int lane = threadIdx.x & 63;
  const int wv   = threadIdx.x >> 6;
  const int v    = blockIdx.x * 4 + wv;
  if (v >= NV) return;

  const float* __restrict__ row = L + (size_t)v * NV;
  const int head     = (v & 1) ? 2 : 0;
  const int extraPos = head ? 0 : (NV - 2);
  const float4* __restrict__ m4 = (const float4*)(row + head);

  const int n0 = lane, n1 = lane + 64, n2 = lane + 128;
  const int o0 = (n0 / 3) * (NV * 3) + (n0 % 3);
  const int o1 = (n1 / 3) * (NV * 3) + (n1 % 3);
  const int o2 = (n2 / 3) * (NV * 3) + (n2 % 3);

  float a0 = 0.f, a1 = 0.f, a2 = 0.f;
  auto walk = [&](unsigned long long m, float src, int col0, int stride) {
    while (m) {
      const int s = (int)__builtin_ctzll(m);
      m &= m - 1;
      const float val =
          __int_as_float(__builtin_amdgcn_readlane(__float_as_int(src), s));
      const int cb = (col0 + s * stride) * 3;
      a0 = fmaf(val, x[cb + o0], a0);
      a1 = fmaf(val, x[cb + o1], a1);
      a2 = fmaf(val, x[cb + o2], a2);
    }
  };
  {
    const bool act = lane < 2;
    const float val = act ? row[extraPos + lane] : 0.f;
    walk(__ballot(act && val != 0.f), val, extraPos, 1);
  }
  for (int it = 0; it < 27; ++it) {
    const int i = it * 64 + lane;
    const bool act = i < MAIN4;
    float4 f = make_float4(0.f, 0.f, 0.f, 0.f);
    if (act) f = m4[i];
    const int cb = head + it * 256;
    walk(__ballot(act && f.x != 0.f), f.x, cb + 0, 4);
    walk(__ballot(act && f.y != 0.f), f.y, cb + 1, 4);
    walk(__ballot(act && f.z != 0.f), f.z, cb + 2, 4);
    walk(__ballot(act && f.w != 0.f), f.w, cb + 3, 4);
  }

  float sq = fmaf(a0, a0, fmaf(a1, a1, a2 * a2));
  #pragma unroll
  for (int o = 32; o > 0; o >>= 1) sq += __shfl_down(sq, o);
  if (lane == 0) atomicAdd(out, sq * SCALE);
}

__global__ void zero_out_kernel(float* p) {
  if (threadIdx.x == 0 && blockIdx.x == 0) p[0] = 0.0f;
}

// ---------------------------------------------------------------------------
extern "C" void kernel_launch(void* const* d_in, const int* in_sizes, int n_in,
                              void* d_out, int out_size, void* d_ws, size_t ws_size,
                              hipStream_t stream) {
  const float* x = (const float*)d_in[0];   // [64, 6890, 3] f32
  const float* L = (const float*)d_in[1];   // [6890, 6890] f32
  float* out = (float*)d_out;               // scalar f32

  const size_t xt_bytes = (size_t)NV * NCOL * sizeof(float);  // ~5.29 MB
  const int grid = (NV + 3) / 4;

  if (ws_size >= xt_bytes) {
    float* Xt = (float*)d_ws;
    transpose_x_kernel<<<(NV * NCOL + 255) / 256, 256, 0, stream>>>(x, Xt, out);
    lap_rows_wave_kernel<<<grid, 256, 0, stream>>>(L, Xt, out);
  } else {
    zero_out_kernel<<<1, 64, 0, stream>>>(out);
    lap_fused_kernel<<<grid, 256, 0, stream>>>(L, x, out);
  }
}